// Round 21
// baseline (107.067 us; speedup 1.0000x reference)
//
#include <hip/hip_runtime.h>
#include <hip/hip_bf16.h>

typedef __attribute__((ext_vector_type(8))) short bf16x8;
typedef __attribute__((ext_vector_type(16))) float f32x16;

#define CDIM 192
#define NTOK 196
#define LTOT 392
#define NBE 64

__device__ __forceinline__ ushort f2bf(float f) {
  uint u = __float_as_uint(f);
  u = (u + 0x7FFFu + ((u >> 16) & 1u)) >> 16;
  return (ushort)u;
}
__device__ __forceinline__ float bf2f(ushort h) {
  return __uint_as_float(((uint)h) << 16);
}
__device__ __forceinline__ uint pk2(float lo, float hi) {
  __hip_bfloat162 t = __float22bfloat162_rn(float2{lo, hi});
  uint r;
  __builtin_memcpy(&r, &t, 4);
  return r;
}
__device__ __forceinline__ float wave_reduce(float a) {
#pragma unroll
  for (int off = 32; off > 0; off >>= 1) a += __shfl_xor(a, off);
  return a;
}
__device__ __forceinline__ void barL() {
  asm volatile("s_waitcnt lgkmcnt(0)" ::: "memory");
  __builtin_amdgcn_s_barrier();
  __builtin_amdgcn_sched_barrier(0);
}

// ---------------- prep: fold BN (bf16 weights), u3/u4/K via wave-reductions ---
__global__ __launch_bounds__(256) void prep_kernel(
    const float* __restrict__ w1, const float* __restrict__ b1, const float* __restrict__ g1,
    const float* __restrict__ be1, const float* __restrict__ m1, const float* __restrict__ v1,
    const float* __restrict__ w2, const float* __restrict__ b2, const float* __restrict__ g2,
    const float* __restrict__ be2, const float* __restrict__ m2, const float* __restrict__ v2,
    const float* __restrict__ w3, const float* __restrict__ b3,
    const float* __restrict__ w4, const float* __restrict__ b4,
    const float* __restrict__ w5, const float* __restrict__ b5,
    ushort* __restrict__ w1b, ushort* __restrict__ w2b,
    float* __restrict__ u3, float* __restrict__ u4, float* __restrict__ cvecs,
    float* __restrict__ Kc) {
  const int bid = blockIdx.x;
  const int wid = threadIdx.x >> 6, lane = threadIdx.x & 63;
  if (bid < NBE) {
    for (int i = bid * 256 + threadIdx.x; i < 74112; i += NBE * 256) {
      if (i < 36864) {
        int o = i / CDIM;
        float inv = g1[o] * rsqrtf(v1[o] + 1e-5f);
        w1b[i] = f2bf(w1[i] * inv);
      } else if (i < 73728) {
        int j = i - 36864; int o = j / CDIM;
        float inv = g2[o] * rsqrtf(v2[o] + 1e-5f);
        w2b[j] = f2bf(w2[j] * inv);
      } else {
        int k = i - 73728; int h = k / CDIM, o = k % CDIM;
        const float* bb = h ? b2 : b1; const float* gg = h ? g2 : g1;
        const float* bee = h ? be2 : be1;
        const float* mm = h ? m2 : m1; const float* vv = h ? v2 : v1;
        float inv = gg[o] * rsqrtf(vv[o] + 1e-5f);
        cvecs[k] = (bb[o] - mm[o]) * inv + bee[o];
      }
    }
  } else if (bid < NBE + 48) {            // u3: wave per output j
    int j = (bid - NBE) * 4 + wid;
    float a = 0.f;
    for (int c = lane; c < CDIM; c += 64) a += w5[c] * w3[c * CDIM + j];
    a = wave_reduce(a);
    if (lane == 0) u3[j] = a;
  } else if (bid < NBE + 48 + 98) {       // u4: wave per output j
    int j = (bid - NBE - 48) * 4 + wid;
    float a = 0.f;
    for (int o = lane; o < 784; o += 64)
      a += w5[CDIM + o] * (w4[o * 784 + j] + w4[o * 784 + j + LTOT]);
    a = wave_reduce(a);
    if (lane == 0) u4[j] = a;
  } else {                                // Kc: single wave
    if (wid == 0) {
      float a = 0.f;
      for (int i = lane; i < CDIM + 784; i += 64)
        a += (i < CDIM) ? w5[i] * b3[i] : w5[i] * b4[i - CDIM];
      a = wave_reduce(a);
      if (lane == 0) Kc[0] = a + b5[0];
    }
  }
}

// chunk tables: g=0 -> rows {0,32,64}; g=1 -> {96,128,160,164(ovl for s)}
__device__ __constant__ int L0S[2][4] = {{0, 32, 64, -1}, {96, 128, 160, 164}};

// ---- K1: phi chunks + s partials (phi never stored). grid 1024=(b,h,g) -----
__global__ __launch_bounds__(384) void phis_kernel(
    const float* __restrict__ x, const float* __restrict__ y,
    const ushort* __restrict__ w1b, const ushort* __restrict__ w2b,
    const float* __restrict__ cvecs, const float* __restrict__ u4,
    float* __restrict__ s_part) {
  const int bid = blockIdx.x;
  const int b = bid >> 2, h = (bid >> 1) & 1, g = bid & 1;
  const float4* src4 = (const float4*)(((h ? y : x) + (size_t)b * NTOK * CDIM));
  const ushort* wb = h ? w2b : w1b;
  __shared__ ushort Abuf[2][32 * CDIM];   // 2 x 12KB
  __shared__ float u4s[100];
  const int tid = threadIdx.x;
  const int rbase = g ? 96 : 0;
  for (int i = tid; i < 100; i += 384) u4s[i] = u4[h * NTOK + rbase + i];

  const int w = tid >> 6, lane = tid & 63;
  const int cl32 = lane & 31, hi = lane >> 5;
  const int c = w * 32 + cl32;            // wave w owns c-tile w (6 waves)

  bf16x8 bfr[12];
#pragma unroll
  for (int kk = 0; kk < 12; kk++)
    bfr[kk] = *(const bf16x8*)(wb + (size_t)c * CDIM + kk * 16 + hi * 8);
  const float csr = cvecs[h * CDIM + c];

  const int nchunks = g ? 4 : 3;
  float sp = 0.f;
  float4 pf[4];
#pragma unroll
  for (int p = 0; p < 4; p++) pf[p] = src4[L0S[g][0] * 48 + p * 384 + tid];

  for (int k = 0; k < 4; k++) {
    if (k >= nchunks) break;
    const int l0 = L0S[g][k];
    ushort* Ab = &Abuf[k & 1][0];
#pragma unroll
    for (int p = 0; p < 4; p++) {         // stage chunk k (consumes pf)
      const int fi = p * 384 + tid;
      const int r = fi / 48, c4 = fi % 48;
      uint2 wv;
      wv.x = pk2(pf[p].x, pf[p].y);
      wv.y = pk2(pf[p].z, pf[p].w);
      uint addr = (uint)(r * 384 + c4 * 8) ^ (uint)((r & 7) << 4);
      *(uint2*)((char*)Ab + addr) = wv;
    }
    if (k + 1 < nchunks) {                // prefetch chunk k+1 (in flight)
#pragma unroll
      for (int p = 0; p < 4; p++)
        pf[p] = src4[L0S[g][k + 1] * 48 + p * 384 + tid];
    }
    __builtin_amdgcn_sched_barrier(0);
    barL();
    f32x16 acc;
#pragma unroll
    for (int e = 0; e < 16; e++) acc[e] = 0.f;
    const uint swz = (uint)((cl32 & 7) << 4);
    __builtin_amdgcn_s_setprio(1);
#pragma unroll
    for (int kk = 0; kk < 12; kk++) {
      uint ad = (uint)(cl32 * 384 + kk * 32 + hi * 16) ^ swz;
      bf16x8 af = *(const bf16x8*)((const char*)Ab + ad);
      acc = __builtin_amdgcn_mfma_f32_32x32x16_bf16(af, bfr[kk], acc, 0, 0, 0);
    }
    __builtin_amdgcn_s_setprio(0);
    const bool ovl = (l0 == 164);
#pragma unroll
    for (int e = 0; e < 16; e++) {
      const int rl = (e & 3) + 8 * (e >> 2) + 4 * hi;
      const int row = l0 + rl;
      if (!ovl || row >= 192) {
        const float v = fmaxf(acc[e] + csr, 0.f);
        sp += u4s[row - rbase] * v;
      }
    }
    // single barrier/chunk is safe: stage(k+1) sits before next barL, and all
    // waves passed this chunk's barL only after prior MFMA reads completed.
  }
  sp += __shfl_xor(sp, 32);
  if (hi == 0) s_part[(size_t)((b * 2 + h) * 2 + g) * CDIM + c] = sp;
}

// ---- K2: W via phi recompute + coeff contraction. grid 1024=(b,h,g) --------
__global__ __launch_bounds__(384) void wrec_kernel(
    const float* __restrict__ x, const float* __restrict__ y,
    const ushort* __restrict__ w1b, const ushort* __restrict__ w2b,
    const float* __restrict__ cvecs, const float* __restrict__ u3,
    const float* __restrict__ s_part, const float* __restrict__ Kc,
    float* __restrict__ Wg) {
  const int bid = blockIdx.x;
  const int b = bid >> 2, h = (bid >> 1) & 1, g = bid & 1;
  const float4* src4 = (const float4*)(((h ? y : x) + (size_t)b * NTOK * CDIM));
  const ushort* wb = h ? w2b : w1b;
  __shared__ ushort Abuf[2][32 * CDIM];
  __shared__ float Wred[6][32];
  const int tid = threadIdx.x;
  const int w = tid >> 6, lane = tid & 63;
  const int cl32 = lane & 31, hi = lane >> 5;
  const int c = w * 32 + cl32;

  bf16x8 bfr[12];
#pragma unroll
  for (int kk = 0; kk < 12; kk++)
    bfr[kk] = *(const bf16x8*)(wb + (size_t)c * CDIM + kk * 16 + hi * 8);
  const float csr = cvecs[h * CDIM + c];
  float cf = u3[c];
#pragma unroll
  for (int q = 0; q < 4; q++) cf += s_part[(size_t)(b * 4 + q) * CDIM + c];
  const float Kv = Kc[0];

  const int nchunks = g ? 4 : 3;
  float4 pf[4];
#pragma unroll
  for (int p = 0; p < 4; p++) pf[p] = src4[L0S[g][0] * 48 + p * 384 + tid];

  for (int k = 0; k < 4; k++) {
    if (k >= nchunks) break;
    const int l0 = L0S[g][k];
    ushort* Ab = &Abuf[k & 1][0];
#pragma unroll
    for (int p = 0; p < 4; p++) {
      const int fi = p * 384 + tid;
      const int r = fi / 48, c4 = fi % 48;
      uint2 wv;
      wv.x = pk2(pf[p].x, pf[p].y);
      wv.y = pk2(pf[p].z, pf[p].w);
      uint addr = (uint)(r * 384 + c4 * 8) ^ (uint)((r & 7) << 4);
      *(uint2*)((char*)Ab + addr) = wv;
    }
    if (k + 1 < nchunks) {
#pragma unroll
      for (int p = 0; p < 4; p++)
        pf[p] = src4[L0S[g][k + 1] * 48 + p * 384 + tid];
    }
    __builtin_amdgcn_sched_barrier(0);
    barL();
    f32x16 acc;
#pragma unroll
    for (int e = 0; e < 16; e++) acc[e] = 0.f;
    const uint swz = (uint)((cl32 & 7) << 4);
    __builtin_amdgcn_s_setprio(1);
#pragma unroll
    for (int kk = 0; kk < 12; kk++) {
      uint ad = (uint)(cl32 * 384 + kk * 32 + hi * 16) ^ swz;
      bf16x8 af = *(const bf16x8*)((const char*)Ab + ad);
      acc = __builtin_amdgcn_mfma_f32_32x32x16_bf16(af, bfr[kk], acc, 0, 0, 0);
    }
    __builtin_amdgcn_s_setprio(0);
    // p[e] = relu(acc+csr)*coeff; butterfly-sum over the 32 c's of this tile
    float pv[16];
#pragma unroll
    for (int e = 0; e < 16; e++) pv[e] = fmaxf(acc[e] + csr, 0.f) * cf;
#pragma unroll
    for (int m = 1; m <= 16; m <<= 1)
#pragma unroll
      for (int e = 0; e < 16; e++) pv[e] += __shfl_xor(pv[e], m);
    if (cl32 == 0) {
#pragma unroll
      for (int e = 0; e < 16; e++) {
        const int rl = (e & 3) + 8 * (e >> 2) + 4 * hi;
        Wred[w][rl] = pv[e];
      }
    }
    barL();
    if (tid < 32) {
      float sw = 0.f;
#pragma unroll
      for (int ww = 0; ww < 6; ww++) sw += Wred[ww][tid];
      Wg[b * LTOT + h * NTOK + l0 + tid] = sw + Kv;  // overlap rows: identical rewrites
    }
  }
}

// ------- K3 out: block = (b, n-tile of 28). out = x*Wx + y*Wy, transposed. ---
__global__ __launch_bounds__(256) void out_kernel(
    const float* __restrict__ x, const float* __restrict__ y,
    const float* __restrict__ Wg, float* __restrict__ out) {
  const int bid = blockIdx.x;
  const int b = bid / 7, nt = bid % 7;
  const int n0 = nt * 28;
  __shared__ float Wl[56];
  __shared__ float tile[28][193];
  const int tid = threadIdx.x;
  if (tid < 56) {
    const int lg = (tid < 28) ? (n0 + tid) : (NTOK + n0 + tid - 28);
    Wl[tid] = Wg[b * LTOT + lg];
  }
  __syncthreads();
  for (int i = tid; i < 28 * 48; i += 256) {
    const int nl = i / 48, c4 = (i % 48) * 4;
    const size_t xi = ((size_t)b * NTOK + n0 + nl) * CDIM + c4;
    const float4 xv = *(const float4*)&x[xi];
    const float4 yv = *(const float4*)&y[xi];
    const float wx = Wl[nl], wy = Wl[28 + nl];
    tile[nl][c4 + 0] = xv.x * wx + yv.x * wy;
    tile[nl][c4 + 1] = xv.y * wx + yv.y * wy;
    tile[nl][c4 + 2] = xv.z * wx + yv.z * wy;
    tile[nl][c4 + 3] = xv.w * wx + yv.w * wy;
  }
  __syncthreads();
  for (int i = tid; i < CDIM * 7; i += 256) {
    const int c = i / 7, nq = i % 7;
    float4 o;
    o.x = tile[nq * 4 + 0][c]; o.y = tile[nq * 4 + 1][c];
    o.z = tile[nq * 4 + 2][c]; o.w = tile[nq * 4 + 3][c];
    *(float4*)&out[((size_t)b * CDIM + c) * NTOK + n0 + nq * 4] = o;
  }
}

extern "C" void kernel_launch(void* const* d_in, const int* in_sizes, int n_in,
                              void* d_out, int out_size, void* d_ws, size_t ws_size,
                              hipStream_t stream) {
  const float* x   = (const float*)d_in[0];
  const float* y   = (const float*)d_in[1];
  const float* w1  = (const float*)d_in[2];
  const float* b1  = (const float*)d_in[3];
  const float* g1  = (const float*)d_in[4];
  const float* be1 = (const float*)d_in[5];
  const float* m1  = (const float*)d_in[6];
  const float* v1  = (const float*)d_in[7];
  const float* w2  = (const float*)d_in[8];
  const float* b2  = (const float*)d_in[9];
  const float* g2  = (const float*)d_in[10];
  const float* be2 = (const float*)d_in[11];
  const float* m2  = (const float*)d_in[12];
  const float* v2  = (const float*)d_in[13];
  const float* w3  = (const float*)d_in[14];
  const float* b3  = (const float*)d_in[15];
  const float* w4  = (const float*)d_in[16];
  const float* b4  = (const float*)d_in[17];
  const float* w5  = (const float*)d_in[18];
  const float* b5  = (const float*)d_in[19];
  float* out = (float*)d_out;

  char* ws = (char*)d_ws;
  ushort* w1b  = (ushort*)ws;             // 73728 B
  ushort* w2b  = (ushort*)(ws + 73728);   // 73728 B
  float* fbase = (float*)(ws + 147456);
  float* u3    = fbase;                   // 192
  float* u4    = fbase + 192;             // 392
  float* cvecs = fbase + 584;             // 384 (c1|c2)
  float* Kc    = fbase + 968;             // 1
  float* s_part = fbase + 976;            // 256*4*192 = 196608
  float* Wg    = fbase + 976 + 196608;    // 256*392 = 100352

  prep_kernel<<<211, 256, 0, stream>>>(w1, b1, g1, be1, m1, v1,
                                       w2, b2, g2, be2, m2, v2,
                                       w3, b3, w4, b4, w5, b5,
                                       w1b, w2b, u3, u4, cvecs, Kc);
  phis_kernel<<<1024, 384, 0, stream>>>(x, y, w1b, w2b, cvecs, u4, s_part);
  wrec_kernel<<<1024, 384, 0, stream>>>(x, y, w1b, w2b, cvecs, u3, s_part, Kc, Wg);
  out_kernel<<<256 * 7, 256, 0, stream>>>(x, y, Wg, out);
}

// Round 22
// 70.375 us; speedup vs baseline: 1.5214x; 1.5214x over previous
//
#include <hip/hip_runtime.h>
#include <hip/hip_bf16.h>

typedef __attribute__((ext_vector_type(8))) short bf16x8;
typedef __attribute__((ext_vector_type(4))) float f32x4;

#define CDIM 192
#define NTOK 196
#define LTOT 392
#define BDIM 256
#define NBE 64

__device__ __forceinline__ ushort f2bf(float f) {
  uint u = __float_as_uint(f);
  u = (u + 0x7FFFu + ((u >> 16) & 1u)) >> 16;
  return (ushort)u;
}
__device__ __forceinline__ float bf2f(ushort h) {
  return __uint_as_float(((uint)h) << 16);
}
__device__ __forceinline__ uint pk2(float lo, float hi) {
  __hip_bfloat162 t = __float22bfloat162_rn(float2{lo, hi});
  uint r;
  __builtin_memcpy(&r, &t, 4);
  return r;
}
__device__ __forceinline__ float wave_reduce(float a) {
#pragma unroll
  for (int off = 32; off > 0; off >>= 1) a += __shfl_xor(a, off);
  return a;
}
__device__ __forceinline__ void barL() {
  asm volatile("s_waitcnt lgkmcnt(0)" ::: "memory");
  __builtin_amdgcn_s_barrier();
  __builtin_amdgcn_sched_barrier(0);
}
// async global->LDS, 16B per lane; dest = wave-uniform base + lane*16 (linear)
__device__ __forceinline__ void gload16(const void* g, void* l) {
  __builtin_amdgcn_global_load_lds(
      (const __attribute__((address_space(1))) void*)g,
      (__attribute__((address_space(3))) void*)l, 16, 0, 0);
}

// ---------------- prep: fold BN (bf16 weights), u3/u4/K, zero s --------------
__global__ __launch_bounds__(256) void prep_kernel(
    const float* __restrict__ w1, const float* __restrict__ b1, const float* __restrict__ g1,
    const float* __restrict__ be1, const float* __restrict__ m1, const float* __restrict__ v1,
    const float* __restrict__ w2, const float* __restrict__ b2, const float* __restrict__ g2,
    const float* __restrict__ be2, const float* __restrict__ m2, const float* __restrict__ v2,
    const float* __restrict__ w3, const float* __restrict__ b3,
    const float* __restrict__ w4, const float* __restrict__ b4,
    const float* __restrict__ w5, const float* __restrict__ b5,
    ushort* __restrict__ w1b, ushort* __restrict__ w2b,
    float* __restrict__ u3, float* __restrict__ u4, float* __restrict__ cvecs,
    float* __restrict__ Kc, float* __restrict__ s) {
  const int bid = blockIdx.x;
  const int wid = threadIdx.x >> 6, lane = threadIdx.x & 63;
  if (bid < NBE) {
    for (int i = bid * BDIM + threadIdx.x; i < 123264; i += NBE * BDIM) {
      if (i < 36864) {
        int o = i / CDIM;
        float inv = g1[o] * rsqrtf(v1[o] + 1e-5f);
        w1b[i] = f2bf(w1[i] * inv);
      } else if (i < 73728) {
        int j = i - 36864; int o = j / CDIM;
        float inv = g2[o] * rsqrtf(v2[o] + 1e-5f);
        w2b[j] = f2bf(w2[j] * inv);
      } else if (i < 74112) {
        int k = i - 73728; int h = k / CDIM, o = k % CDIM;
        const float* bb = h ? b2 : b1; const float* gg = h ? g2 : g1;
        const float* bee = h ? be2 : be1;
        const float* mm = h ? m2 : m1; const float* vv = h ? v2 : v1;
        float inv = gg[o] * rsqrtf(vv[o] + 1e-5f);
        cvecs[k] = (bb[o] - mm[o]) * inv + bee[o];
      } else {
        s[i - 74112] = 0.f;
      }
    }
  } else if (bid < NBE + 48) {            // u3: wave per output j
    int j = (bid - NBE) * 4 + wid;
    float a = 0.f;
    for (int c = lane; c < CDIM; c += 64) a += w5[c] * w3[c * CDIM + j];
    a = wave_reduce(a);
    if (lane == 0) u3[j] = a;
  } else if (bid < NBE + 48 + 98) {       // u4: wave per output j
    int j = (bid - NBE - 48) * 4 + wid;
    float a = 0.f;
    for (int o = lane; o < 784; o += 64)
      a += w5[CDIM + o] * (w4[o * 784 + j] + w4[o * 784 + j + LTOT]);
    a = wave_reduce(a);
    if (lane == 0) u4[j] = a;
  } else {                                // Kc: single wave
    if (wid == 0) {
      float a = 0.f;
      for (int i = lane; i < CDIM + 784; i += 64)
        a += (i < CDIM) ? w5[i] * b3[i] : w5[i] * b4[i - CDIM];
      a = wave_reduce(a);
      if (lane == 0) Kc[0] = a + b5[0];
    }
  }
}

// -------- phi v12: global_load_lds fp32 staging (src-swizzled), cvt at read --
// Block = (b,h). 7 rounds of 32 rows; counted vmcnt(6); Obuf coalesced dump.
__global__ __launch_bounds__(256) void phi_kernel(
    const float* __restrict__ x, const float* __restrict__ y,
    const ushort* __restrict__ w1b, const ushort* __restrict__ w2b,
    const float* __restrict__ cvecs, const float* __restrict__ u4,
    ushort* __restrict__ phiT, float* __restrict__ s) {
  const int bh = blockIdx.x, b = bh >> 1, h = bh & 1;
  const float* __restrict__ src = (h ? y : x) + (size_t)b * NTOK * CDIM;
  const ushort* __restrict__ wb = h ? w2b : w1b;
  __shared__ float Af[2][32 * CDIM];      // 2 x 24KB fp32, DMA linear dest
  __shared__ ushort Obuf[32 * CDIM];      // 12KB bf16, swz ^(row&7)<<4
  __shared__ float u4s[224];
  __shared__ float cs[CDIM];
  const int tid = threadIdx.x;
  for (int i = tid; i < 224; i += BDIM) u4s[i] = (i < NTOK) ? u4[h * NTOK + i] : 0.f;
  for (int i = tid; i < CDIM; i += BDIM) cs[i] = cvecs[h * CDIM + i];

  const int wid = tid >> 6, lane = tid & 63;
  const int lrow = lane & 15, kgrp = lane >> 4;
  const int cbase = wid * 48 + lrow;      // wave owns channels [wid*48, +48)

  bf16x8 bfr[3][6];                       // B-fragments, loaded once
#pragma unroll
  for (int ct = 0; ct < 3; ct++)
#pragma unroll
    for (int kk = 0; kk < 6; kk++)
      bfr[ct][kk] = *(const bf16x8*)(wb + (size_t)(cbase + ct * 16) * CDIM + kk * 32 + kgrp * 8);
  __syncthreads();                        // vmcnt(0) baseline: bfr/u4s/cs done
  const float csr[3] = {cs[cbase], cs[cbase + 16], cs[cbase + 32]};

  // stage round r: 24 x gload16; wave wid issues j=0..5. Source pre-swizzled
  // (oin ^ (row&15)<<4) so LDS holds swizzled fp32 rows; dest stays linear.
  auto issue = [&](int r) {
    const int row0 = r * 32;
#pragma unroll
    for (int j = 0; j < 6; j++) {
      const int slot = wid * 6 + j;
      const int lin = slot * 1024 + lane * 16;   // this lane's dest byte
      const int row = lin / 768;
      const int oin = lin - row * 768;
      const int srow = min(row0 + row, NTOK - 1);  // clamp tail rows
      const int goff = srow * 768 + (oin ^ ((row & 15) << 4));
      gload16((const char*)src + goff, (char*)&Af[r & 1][0] + slot * 1024);
    }
  };
  issue(0);

  float sp[3] = {0.f, 0.f, 0.f};
  for (int r = 0; r < 7; r++) {
    if (r < 6) {
      issue(r + 1);                       // next round's 6 stay in flight
      asm volatile("s_waitcnt vmcnt(6)" ::: "memory");
    } else {
      asm volatile("s_waitcnt vmcnt(0)" ::: "memory");
    }
    __builtin_amdgcn_sched_barrier(0);
    barL();                               // Af[r&1] visible to all waves
    const char* Ab = (const char*)&Af[r & 1][0];
#pragma unroll
    for (int tt = 0; tt < 2; tt++) {
      const int l0 = r * 32 + tt * 16;
      if (l0 < NTOK) {
        bf16x8 afr[6];
#pragma unroll
        for (int kk = 0; kk < 6; kk++) {
          const int row = tt * 16 + lrow;
          const uint m = (uint)((row & 15) << 4);
          const uint colb = (uint)((kk * 32 + kgrp * 8) * 4);
          const f32x4 f0 = *(const f32x4*)(Ab + row * 768 + (int)(colb ^ m));
          const f32x4 f1 = *(const f32x4*)(Ab + row * 768 + (int)((colb + 16) ^ m));
          uint4 au;
          au.x = pk2(f0[0], f0[1]); au.y = pk2(f0[2], f0[3]);
          au.z = pk2(f1[0], f1[1]); au.w = pk2(f1[2], f1[3]);
          __builtin_memcpy(&afr[kk], &au, 16);
        }
        f32x4 acc0 = {0.f,0.f,0.f,0.f}, acc1 = {0.f,0.f,0.f,0.f}, acc2 = {0.f,0.f,0.f,0.f};
        __builtin_amdgcn_s_setprio(1);
#pragma unroll
        for (int kk = 0; kk < 6; kk++) {
          acc0 = __builtin_amdgcn_mfma_f32_16x16x32_bf16(afr[kk], bfr[0][kk], acc0, 0, 0, 0);
          acc1 = __builtin_amdgcn_mfma_f32_16x16x32_bf16(afr[kk], bfr[1][kk], acc1, 0, 0, 0);
          acc2 = __builtin_amdgcn_mfma_f32_16x16x32_bf16(afr[kk], bfr[2][kk], acc2, 0, 0, 0);
        }
        __builtin_amdgcn_s_setprio(0);
        const int ll = tt * 16 + 4 * kgrp;  // local row base in [0,32)
        const float4 u4v = *(const float4*)&u4s[r * 32 + ll];
        auto epi = [&](const f32x4& acc, int ct, float& spc) {
          const float v0 = fmaxf(acc[0] + csr[ct], 0.f);
          const float v1 = fmaxf(acc[1] + csr[ct], 0.f);
          const float v2 = fmaxf(acc[2] + csr[ct], 0.f);
          const float v3 = fmaxf(acc[3] + csr[ct], 0.f);
          const uint p01 = pk2(v0, v1), p23 = pk2(v2, v3);
          const int c = cbase + ct * 16;
#pragma unroll
          for (int j = 0; j < 4; j++) {
            const int row = ll + j;
            uint addr = (uint)(row * (CDIM * 2) + c * 2);
            addr ^= (uint)((row & 7) << 4);
            const uint piece = (j == 0) ? (p01 & 0xFFFFu) : (j == 1) ? (p01 >> 16)
                             : (j == 2) ? (p23 & 0xFFFFu) : (p23 >> 16);
            *(ushort*)((char*)Obuf + addr) = (ushort)piece;
            const float vj = (j == 0) ? v0 : (j == 1) ? v1 : (j == 2) ? v2 : v3;
            if (l0 - tt * 16 + row < NTOK) spc += u4v.x * 0.f + u4s[r * 32 + row] * vj;
          }
        };
        // (simplified s accumulation: guard each row, read u4s directly)
        epi(acc0, 0, sp[0]); epi(acc1, 1, sp[1]); epi(acc2, 2, sp[2]);
      }
    }
    barL();                               // epi Obuf writes visible
    // dump Obuf -> phiT, coalesced 16B/lane
    const int rows = min(32, NTOK - r * 32);
    const int nel = rows * CDIM;
    ushort* dst = phiT + ((size_t)b * LTOT + h * NTOK + r * 32) * CDIM;
    for (int off = tid * 8; off < nel; off += BDIM * 8) {
      const int row = off / CDIM;
      uint addr = (uint)(off * 2) ^ (uint)((row & 7) << 4);
      uint4 v = *(const uint4*)((const char*)Obuf + addr);
      *(uint4*)(dst + off) = v;
    }
    // next round's first barL orders these ds_reads before Obuf reuse.
  }
#pragma unroll
  for (int ct = 0; ct < 3; ct++) {
    float v = sp[ct];
    v += __shfl_xor(v, 16);
    v += __shfl_xor(v, 32);
    if (kgrp == 0) atomicAdd(&s[b * CDIM + cbase + ct * 16], v);
  }
}

// ------- fused W + out: block = (b, n-tile of 28). 196 = 7*28, no masks. -----
__global__ __launch_bounds__(256) void wout_kernel(
    const float* __restrict__ x, const float* __restrict__ y,
    const ushort* __restrict__ phiT, const float* __restrict__ s,
    const float* __restrict__ u3, const float* __restrict__ Kc,
    float* __restrict__ out) {
  const int bid = blockIdx.x;
  const int b = bid / 7, nt = bid % 7;
  const int n0 = nt * 28;
  __shared__ float coeff[CDIM];
  __shared__ float Wl[56];
  __shared__ float tile[28][193];
  const int tid = threadIdx.x;
  for (int i = tid; i < CDIM; i += BDIM) coeff[i] = u3[i] + s[b * CDIM + i];
  __syncthreads();
  const int wv = tid >> 6, lane = tid & 63;
  const int rloc = wv * 16 + (lane >> 2), g4 = lane & 3;
  if (rloc < 56) {
    const int lg = (rloc < 28) ? (n0 + rloc) : (NTOK + n0 + rloc - 28);
    const ushort* p = phiT + ((size_t)b * LTOT + lg) * CDIM + g4 * 48;
    float acc = 0.f;
#pragma unroll
    for (int q = 0; q < 12; q++) {
      ushort4 v = *(const ushort4*)(p + q * 4);
      const float* cf = &coeff[g4 * 48 + q * 4];
      acc += cf[0] * bf2f(v.x) + cf[1] * bf2f(v.y) +
             cf[2] * bf2f(v.z) + cf[3] * bf2f(v.w);
    }
    acc += __shfl_xor(acc, 1);
    acc += __shfl_xor(acc, 2);
    if (g4 == 0) Wl[rloc] = acc + Kc[0];
  }
  __syncthreads();
  for (int i = tid; i < 28 * 48; i += BDIM) {
    const int nl = i / 48, c4 = (i % 48) * 4;
    const size_t xi = ((size_t)b * NTOK + n0 + nl) * CDIM + c4;
    const float4 xv = *(const float4*)&x[xi];
    const float4 yv = *(const float4*)&y[xi];
    const float wx = Wl[nl], wy = Wl[28 + nl];
    tile[nl][c4 + 0] = xv.x * wx + yv.x * wy;
    tile[nl][c4 + 1] = xv.y * wx + yv.y * wy;
    tile[nl][c4 + 2] = xv.z * wx + yv.z * wy;
    tile[nl][c4 + 3] = xv.w * wx + yv.w * wy;
  }
  __syncthreads();
  for (int i = tid; i < CDIM * 7; i += BDIM) {
    const int c = i / 7, nq = i % 7;
    float4 o;
    o.x = tile[nq * 4 + 0][c]; o.y = tile[nq * 4 + 1][c];
    o.z = tile[nq * 4 + 2][c]; o.w = tile[nq * 4 + 3][c];
    *(float4*)&out[((size_t)b * CDIM + c) * NTOK + n0 + nq * 4] = o;
  }
}

extern "C" void kernel_launch(void* const* d_in, const int* in_sizes, int n_in,
                              void* d_out, int out_size, void* d_ws, size_t ws_size,
                              hipStream_t stream) {
  const float* x   = (const float*)d_in[0];
  const float* y   = (const float*)d_in[1];
  const float* w1  = (const float*)d_in[2];
  const float* b1  = (const float*)d_in[3];
  const float* g1  = (const float*)d_in[4];
  const float* be1 = (const float*)d_in[5];
  const float* m1  = (const float*)d_in[6];
  const float* v1  = (const float*)d_in[7];
  const float* w2  = (const float*)d_in[8];
  const float* b2  = (const float*)d_in[9];
  const float* g2  = (const float*)d_in[10];
  const float* be2 = (const float*)d_in[11];
  const float* m2  = (const float*)d_in[12];
  const float* v2  = (const float*)d_in[13];
  const float* w3  = (const float*)d_in[14];
  const float* b3  = (const float*)d_in[15];
  const float* w4  = (const float*)d_in[16];
  const float* b4  = (const float*)d_in[17];
  const float* w5  = (const float*)d_in[18];
  const float* b5  = (const float*)d_in[19];
  float* out = (float*)d_out;

  char* ws = (char*)d_ws;
  ushort* w1b  = (ushort*)ws;             // 73728 B
  ushort* w2b  = (ushort*)(ws + 73728);   // 73728 B
  float* fbase = (float*)(ws + 147456);
  float* u3    = fbase;                   // 192
  float* u4    = fbase + 192;             // 392
  float* cvecs = fbase + 584;             // 384 (c1|c2)
  float* Kc    = fbase + 968;             // 1
  float* s     = fbase + 976;             // 256*192 = 49152
  // phiT in workspace (ws >= 256MB per poison-fill evidence); must not alias
  // d_out (wout reads phiT while writing out).
  ushort* phiT = (ushort*)(ws + (1 << 22));  // 38.5 MB at +4MB

  prep_kernel<<<211, BDIM, 0, stream>>>(w1, b1, g1, be1, m1, v1,
                                        w2, b2, g2, be2, m2, v2,
                                        w3, b3, w4, b4, w5, b5,
                                        w1b, w2b, u3, u4, cvecs, Kc, s);
  phi_kernel<<<512, BDIM, 0, stream>>>(x, y, w1b, w2b, cvecs, u4, phiT, s);
  wout_kernel<<<256 * 7, BDIM, 0, stream>>>(x, y, phiT, s, u3, Kc, out);
}

// Round 23
// 61.229 us; speedup vs baseline: 1.7486x; 1.1494x over previous
//
#include <hip/hip_runtime.h>
#include <hip/hip_bf16.h>

typedef __attribute__((ext_vector_type(8))) short bf16x8;
typedef __attribute__((ext_vector_type(4))) float f32x4;

#define CDIM 192
#define NTOK 196
#define LTOT 392
#define NBE 64

__device__ __forceinline__ ushort f2bf(float f) {
  uint u = __float_as_uint(f);
  u = (u + 0x7FFFu + ((u >> 16) & 1u)) >> 16;
  return (ushort)u;
}
__device__ __forceinline__ float bf2f(ushort h) {
  return __uint_as_float(((uint)h) << 16);
}
__device__ __forceinline__ uint pk2(float lo, float hi) {
  __hip_bfloat162 t = __float22bfloat162_rn(float2{lo, hi});
  uint r;
  __builtin_memcpy(&r, &t, 4);
  return r;
}
__device__ __forceinline__ float wave_reduce(float a) {
#pragma unroll
  for (int off = 32; off > 0; off >>= 1) a += __shfl_xor(a, off);
  return a;
}
// Raw barrier: LDS-visibility only (lgkmcnt); does NOT drain in-flight global
// loads (unlike __syncthreads' vmcnt(0) drain) — keeps prefetches pipelined.
__device__ __forceinline__ void barL() {
  asm volatile("s_waitcnt lgkmcnt(0)" ::: "memory");
  __builtin_amdgcn_s_barrier();
  __builtin_amdgcn_sched_barrier(0);
}

// ---------------- prep: fold BN (bf16 weights), u3/u4/K via wave-reductions ---
__global__ __launch_bounds__(256) void prep_kernel(
    const float* __restrict__ w1, const float* __restrict__ b1, const float* __restrict__ g1,
    const float* __restrict__ be1, const float* __restrict__ m1, const float* __restrict__ v1,
    const float* __restrict__ w2, const float* __restrict__ b2, const float* __restrict__ g2,
    const float* __restrict__ be2, const float* __restrict__ m2, const float* __restrict__ v2,
    const float* __restrict__ w3, const float* __restrict__ b3,
    const float* __restrict__ w4, const float* __restrict__ b4,
    const float* __restrict__ w5, const float* __restrict__ b5,
    ushort* __restrict__ w1b, ushort* __restrict__ w2b,
    float* __restrict__ u3, float* __restrict__ u4, float* __restrict__ cvecs,
    float* __restrict__ Kc) {
  const int bid = blockIdx.x;
  const int wid = threadIdx.x >> 6, lane = threadIdx.x & 63;
  if (bid < NBE) {
    for (int i = bid * 256 + threadIdx.x; i < 74112; i += NBE * 256) {
      if (i < 36864) {
        int o = i / CDIM;
        float inv = g1[o] * rsqrtf(v1[o] + 1e-5f);
        w1b[i] = f2bf(w1[i] * inv);
      } else if (i < 73728) {
        int j = i - 36864; int o = j / CDIM;
        float inv = g2[o] * rsqrtf(v2[o] + 1e-5f);
        w2b[j] = f2bf(w2[j] * inv);
      } else {
        int k = i - 73728; int h = k / CDIM, o = k % CDIM;
        const float* bb = h ? b2 : b1; const float* gg = h ? g2 : g1;
        const float* bee = h ? be2 : be1;
        const float* mm = h ? m2 : m1; const float* vv = h ? v2 : v1;
        float inv = gg[o] * rsqrtf(vv[o] + 1e-5f);
        cvecs[k] = (bb[o] - mm[o]) * inv + bee[o];
      }
    }
  } else if (bid < NBE + 48) {            // u3: wave per output j
    int j = (bid - NBE) * 4 + wid;
    float a = 0.f;
    for (int c = lane; c < CDIM; c += 64) a += w5[c] * w3[c * CDIM + j];
    a = wave_reduce(a);
    if (lane == 0) u3[j] = a;
  } else if (bid < NBE + 48 + 98) {       // u4: wave per output j
    int j = (bid - NBE - 48) * 4 + wid;
    float a = 0.f;
    for (int o = lane; o < 784; o += 64)
      a += w5[CDIM + o] * (w4[o * 784 + j] + w4[o * 784 + j + LTOT]);
    a = wave_reduce(a);
    if (lane == 0) u4[j] = a;
  } else {                                // Kc: single wave
    if (wid == 0) {
      float a = 0.f;
      for (int i = lane; i < CDIM + 784; i += 64)
        a += (i < CDIM) ? w5[i] * b3[i] : w5[i] * b4[i - CDIM];
      a = wave_reduce(a);
      if (lane == 0) Kc[0] = a + b5[0];
    }
  }
}

// --- fully fused: phi (in LDS) + s + W + out.  1 block per b, 12 waves. ------
// LDS: phiL[404*192]bf16 swz ^(l&7)<<4 | u4s[408] | csL[384] | sArr[192] | Wl[392]
#define PHIL_BYTES (404 * 384)
#define OFF_U4S PHIL_BYTES
#define OFF_CSL (OFF_U4S + 1632)
#define OFF_SARR (OFF_CSL + 1536)
#define OFF_WL (OFF_SARR + 768)
#define SMEM_BYTES (OFF_WL + 1568)

extern __shared__ char smem[];

__global__ __launch_bounds__(768, 1) void fused_kernel(
    const float* __restrict__ x, const float* __restrict__ y,
    const ushort* __restrict__ w1b, const ushort* __restrict__ w2b,
    const float* __restrict__ cvecs, const float* __restrict__ u4,
    const float* __restrict__ u3, const float* __restrict__ Kc,
    float* __restrict__ out) {
  const int b = blockIdx.x;
  ushort* phiL = (ushort*)smem;
  float* u4s = (float*)(smem + OFF_U4S);
  float* csL = (float*)(smem + OFF_CSL);
  float* sArr = (float*)(smem + OFF_SARR);
  float* Wl = (float*)(smem + OFF_WL);
  const int tid = threadIdx.x;
  for (int i = tid; i < 408; i += 768) u4s[i] = (i < LTOT) ? u4[i] : 0.f;
  for (int i = tid; i < 384; i += 768) csL[i] = cvecs[i];

  const int w = tid >> 6, lane = tid & 63;
  const int lrow = lane & 15, kgrp = lane >> 4;
  const int c = w * 16 + lrow;            // wave w owns c-tile w (12 waves)

  bf16x8 bfr[6];                          // current half's B-frags
#pragma unroll
  for (int kk = 0; kk < 6; kk++)
    bfr[kk] = *(const bf16x8*)(w1b + (size_t)c * CDIM + kk * 32 + kgrp * 8);

  const float4* xb4 = (const float4*)(x + (size_t)b * NTOK * CDIM);
  const float4* yb4 = (const float4*)(y + (size_t)b * NTOK * CDIM);
  float4 pfA[7], pfB[6];
  float sp = 0.f;

// chunk geometry: part0 = rows 0..111 (7 tiles, 5376 f4, no mask),
//                 part1 = rows 112..195 (6 tiles, 4032 f4, masked)
#define LOADC(PF, CNT, NF4, SRC4, ROW0) do {                                   \
  _Pragma("unroll")                                                            \
  for (int p = 0; p < (CNT); p++) {                                            \
    const int fi = p * 768 + tid;                                              \
    (PF)[p] = (fi < (NF4)) ? (SRC4)[(ROW0) * 48 + fi]                          \
                           : float4{0.f, 0.f, 0.f, 0.f};                       \
  } } while (0)

#define STAGE(PF, CNT, NF4, H, ROW0) do {                                      \
  _Pragma("unroll")                                                            \
  for (int p = 0; p < (CNT); p++) {                                            \
    const int fi = p * 768 + tid;                                              \
    if (fi < (NF4)) {                                                          \
      const int l = (H) * NTOK + (ROW0) + fi / 48;                             \
      const int c4 = fi % 48;                                                  \
      uint2 wv;                                                                \
      wv.x = pk2((PF)[p].x, (PF)[p].y);                                        \
      wv.y = pk2((PF)[p].z, (PF)[p].w);                                        \
      uint addr = (uint)(l * 384 + c4 * 8) ^ (uint)((l & 7) << 4);             \
      *(uint2*)((char*)phiL + addr) = wv;                                      \
    } } } while (0)

#define MFMA_EPI(H, ROW0, NT, CSR) do {                                        \
  f32x4 acc[7];                                                                \
  _Pragma("unroll")                                                            \
  for (int tt = 0; tt < 7; tt++) acc[tt] = f32x4{0.f, 0.f, 0.f, 0.f};          \
  _Pragma("unroll")                                                            \
  for (int tt = 0; tt < 7; tt++) if (tt < (NT)) {                              \
    const int l0 = (H) * NTOK + (ROW0) + tt * 16 + lrow;                       \
    bf16x8 af[6];                                                              \
    _Pragma("unroll")                                                          \
    for (int kk = 0; kk < 6; kk++) {                                           \
      uint ad = (uint)(l0 * 384 + kk * 64 + kgrp * 16) ^ (uint)((l0 & 7) << 4);\
      af[kk] = *(const bf16x8*)((const char*)phiL + ad);                       \
    }                                                                          \
    _Pragma("unroll")                                                          \
    for (int kk = 0; kk < 6; kk++)                                             \
      acc[tt] = __builtin_amdgcn_mfma_f32_16x16x32_bf16(af[kk], bfr[kk],       \
                                                        acc[tt], 0, 0, 0);    \
  }                                                                            \
  barL(); /* all waves' A reads drained before phi overwrites */               \
  _Pragma("unroll")                                                            \
  for (int tt = 0; tt < 7; tt++) if (tt < (NT)) {                              \
    const float v0 = fmaxf(acc[tt][0] + (CSR), 0.f);                           \
    const float v1 = fmaxf(acc[tt][1] + (CSR), 0.f);                           \
    const float v2 = fmaxf(acc[tt][2] + (CSR), 0.f);                           \
    const float v3 = fmaxf(acc[tt][3] + (CSR), 0.f);                           \
    const uint p01 = pk2(v0, v1), p23 = pk2(v2, v3);                           \
    const int rw0 = (ROW0) + tt * 16 + 4 * kgrp;                               \
    _Pragma("unroll")                                                          \
    for (int j = 0; j < 4; j++) {                                              \
      const int row = rw0 + j;                                                 \
      if (row < NTOK) {                                                        \
        const int l = (H) * NTOK + row;                                        \
        uint addr = (uint)(l * 384 + c * 2) ^ (uint)((l & 7) << 4);            \
        const uint piece = (j == 0) ? (p01 & 0xFFFFu) : (j == 1) ? (p01 >> 16) \
                         : (j == 2) ? (p23 & 0xFFFFu) : (p23 >> 16);           \
        *(ushort*)((char*)phiL + addr) = (ushort)piece;                        \
        const float vj = (j == 0) ? v0 : (j == 1) ? v1 : (j == 2) ? v2 : v3;   \
        sp += u4s[l] * vj;                                                     \
      } } } } while (0)

  LOADC(pfA, 7, 5376, xb4, 0);            // chunk0 (x rows 0..111)
  LOADC(pfB, 6, 4032, xb4, 112);          // chunk1 (x rows 112..195)
  // chunk0
  STAGE(pfA, 7, 5376, 0, 0);              // progressive vmcnt drain
  LOADC(pfA, 7, 5376, yb4, 0);            // chunk2 in flight (2-chunk lead)
  barL();
  const float csr0 = csL[c], csr1 = csL[CDIM + c];
  MFMA_EPI(0, 0, 7, csr0);
  // chunk1
  STAGE(pfB, 6, 4032, 0, 112);
  LOADC(pfB, 6, 4032, yb4, 112);          // chunk3 in flight
  barL();
  MFMA_EPI(0, 112, 6, csr0);
  // switch B-frags to half 1 (L2-hot reload; covered by chunk2 stage wait)
#pragma unroll
  for (int kk = 0; kk < 6; kk++)
    bfr[kk] = *(const bf16x8*)(w2b + (size_t)c * CDIM + kk * 32 + kgrp * 8);
  // chunk2
  STAGE(pfA, 7, 5376, 1, 0);
  barL();
  MFMA_EPI(1, 0, 7, csr1);
  // chunk3
  STAGE(pfB, 6, 4032, 1, 112);
  barL();
  MFMA_EPI(1, 112, 6, csr1);

  // s reduction (c fixed per lane) -> sArr -> coeff
  sp += __shfl_xor(sp, 16);
  sp += __shfl_xor(sp, 32);
  if (kgrp == 0) sArr[c] = sp;
  barL();
  for (int i = tid; i < CDIM; i += 768) sArr[i] = u3[i] + sArr[i];
  barL();

  // W phase: MFMA lane layout (16 rows x 4 kgrp per wave) -> bank-balanced
  const float Kv = Kc[0];
#pragma unroll
  for (int p = 0; p < 3; p++) {
    const int row = p * 192 + w * 16 + lrow;
    float acc = 0.f;
    if (row < LTOT) {
#pragma unroll
      for (int kk = 0; kk < 6; kk++) {
        const int c0 = kk * 32 + kgrp * 8;
        uint addr = (uint)(row * 384 + c0 * 2) ^ (uint)((row & 7) << 4);
        const uint4 pv = *(const uint4*)((const char*)phiL + addr);
        const float4 cfa = *(const float4*)&sArr[c0];
        const float4 cfb = *(const float4*)&sArr[c0 + 4];
        acc += cfa.x * bf2f((ushort)pv.x) + cfa.y * bf2f((ushort)(pv.x >> 16))
             + cfa.z * bf2f((ushort)pv.y) + cfa.w * bf2f((ushort)(pv.y >> 16))
             + cfb.x * bf2f((ushort)pv.z) + cfb.y * bf2f((ushort)(pv.z >> 16))
             + cfb.z * bf2f((ushort)pv.w) + cfb.w * bf2f((ushort)(pv.w >> 16));
      }
    }
    acc += __shfl_xor(acc, 16);
    acc += __shfl_xor(acc, 32);
    if (kgrp == 0 && row < LTOT) Wl[row] = acc + Kv;
  }

  // out phase: 7 n-tiles of 28; tileF (stride 196, b128 writes) over dead phiL
  float* tileF = (float*)smem;
  const float* xb = x + (size_t)b * NTOK * CDIM;
  const float* yb = y + (size_t)b * NTOK * CDIM;
  float4 pxA[2], pyA[2], pxB[2], pyB[2];

#define LOADT(NT, PX, PY) do {                                                 \
  if ((NT) < 7) {                                                              \
    _Pragma("unroll")                                                          \
    for (int p = 0; p < 2; p++) {                                              \
      const int i = p * 768 + tid;                                             \
      if (i < 1344) {                                                          \
        const size_t xi = (size_t)((NT) * 28 + i / 48) * CDIM + (i % 48) * 4;  \
        (PX)[p] = *(const float4*)&xb[xi];                                     \
        (PY)[p] = *(const float4*)&yb[xi];                                     \
      } } } } while (0)

#define COMBINE(N0, PX, PY) do {                                               \
  _Pragma("unroll")                                                            \
  for (int p = 0; p < 2; p++) {                                                \
    const int i = p * 768 + tid;                                               \
    if (i < 1344) {                                                            \
      const int nl = i / 48, c4 = (i % 48) * 4;                                \
      const float wx = Wl[(N0) + nl], wy = Wl[NTOK + (N0) + nl];               \
      float4 o;                                                                \
      o.x = (PX)[p].x * wx + (PY)[p].x * wy;                                   \
      o.y = (PX)[p].y * wx + (PY)[p].y * wy;                                   \
      o.z = (PX)[p].z * wx + (PY)[p].z * wy;                                   \
      o.w = (PX)[p].w * wx + (PY)[p].w * wy;                                   \
      *(float4*)&tileF[nl * 196 + c4] = o;                                     \
    } } } while (0)

  LOADT(0, pxA, pyA);
  LOADT(1, pxB, pyB);
  for (int nt = 0; nt < 7; nt++) {
    const int n0 = nt * 28;
    barL();  // nt=0: W reads of phiL + Wl writes done; else: prev store done
    if (nt & 1) { COMBINE(n0, pxB, pyB); LOADT(nt + 2, pxB, pyB); }
    else        { COMBINE(n0, pxA, pyA); LOADT(nt + 2, pxA, pyA); }
    barL();  // tile written
#pragma unroll
    for (int p = 0; p < 2; p++) {
      const int i = p * 768 + tid;
      if (i < 1344) {
        const int cc = i / 7, nq = i % 7;
        float4 o;
        o.x = tileF[(nq * 4 + 0) * 196 + cc];
        o.y = tileF[(nq * 4 + 1) * 196 + cc];
        o.z = tileF[(nq * 4 + 2) * 196 + cc];
        o.w = tileF[(nq * 4 + 3) * 196 + cc];
        *(float4*)&out[((size_t)b * CDIM + cc) * NTOK + n0 + nq * 4] = o;
      }
    }
  }
}

extern "C" void kernel_launch(void* const* d_in, const int* in_sizes, int n_in,
                              void* d_out, int out_size, void* d_ws, size_t ws_size,
                              hipStream_t stream) {
  const float* x   = (const float*)d_in[0];
  const float* y   = (const float*)d_in[1];
  const float* w1  = (const float*)d_in[2];
  const float* b1  = (const float*)d_in[3];
  const float* g1  = (const float*)d_in[4];
  const float* be1 = (const float*)d_in[5];
  const float* m1  = (const float*)d_in[6];
  const float* v1  = (const float*)d_in[7];
  const float* w2  = (const float*)d_in[8];
  const float* b2  = (const float*)d_in[9];
  const float* g2  = (const float*)d_in[10];
  const float* be2 = (const float*)d_in[11];
  const float* m2  = (const float*)d_in[12];
  const float* v2  = (const float*)d_in[13];
  const float* w3  = (const float*)d_in[14];
  const float* b3  = (const float*)d_in[15];
  const float* w4  = (const float*)d_in[16];
  const float* b4  = (const float*)d_in[17];
  const float* w5  = (const float*)d_in[18];
  const float* b5  = (const float*)d_in[19];
  float* out = (float*)d_out;

  char* ws = (char*)d_ws;
  ushort* w1b  = (ushort*)ws;             // 73728 B
  ushort* w2b  = (ushort*)(ws + 73728);   // 73728 B
  float* fbase = (float*)(ws + 147456);
  float* u3    = fbase;                   // 192
  float* u4    = fbase + 192;             // 392
  float* cvecs = fbase + 584;             // 384 (c1|c2)
  float* Kc    = fbase + 968;             // 1

  prep_kernel<<<211, 256, 0, stream>>>(w1, b1, g1, be1, m1, v1,
                                       w2, b2, g2, be2, m2, v2,
                                       w3, b3, w4, b4, w5, b5,
                                       w1b, w2b, u3, u4, cvecs, Kc);
  fused_kernel<<<256, 768, SMEM_BYTES, stream>>>(x, y, w1b, w2b, cvecs, u4,
                                                 u3, Kc, out);
}